// Round 3
// baseline (1410.505 us; speedup 1.0000x reference)
//
#include <hip/hip_runtime.h>
#include <hip/hip_bf16.h>

typedef __attribute__((ext_vector_type(4))) float f32x4;
typedef __attribute__((ext_vector_type(8))) __bf16 bf16x8;
typedef __attribute__((ext_vector_type(8))) unsigned short u16x8;
typedef __attribute__((ext_vector_type(4))) unsigned short u16x4;

constexpr int KCH = 64;   // chunks over S=4096
constexpr int LCH = 64;   // steps per chunk
constexpr int CH  = 8192; // channels = B*D

// ---------- ws layout (bytes), total 20 MB ----------
// Whi bf16 [g][h][o][k]: 0       .. +2097152
// Wlo bf16 [g][h][o][k]: 2097152 .. +2097152
// summ f32x4 [KCH][CH]:  4194304 .. +8388608
// states f32x4 [KCH][CH]:12582912 .. +8388608

__device__ inline unsigned short f2bf(float f) {
  return __builtin_bit_cast(unsigned short, __float2bfloat16(f));
}
__device__ inline float bf2f(unsigned short u) {
  return __builtin_bit_cast(float, (unsigned)u << 16);
}

__global__ __launch_bounds__(256) void cvt_w(const float* __restrict__ Wz,
                                             const float* __restrict__ Wi,
                                             const float* __restrict__ Wf,
                                             const float* __restrict__ Wo,
                                             unsigned short* __restrict__ Whi,
                                             unsigned short* __restrict__ Wlo) {
  int i = blockIdx.x * 256 + threadIdx.x;   // 262144 threads, 4 elems each
  int flat = i << 2;                        // 0 .. 1048575
  int g = flat >> 18;
  int rest = flat & 262143;                 // [h][o][k] as in input
  const float* src = (g == 0) ? Wz : (g == 1) ? Wi : (g == 2) ? Wf : Wo;
  f32x4 v = *(const f32x4*)(src + rest);
  u16x4 h, l;
#pragma unroll
  for (int j = 0; j < 4; ++j) {
    h[j] = f2bf(v[j]);
    l[j] = f2bf(v[j] - bf2f(h[j]));
  }
  *(u16x4*)(Whi + flat) = h;
  *(u16x4*)(Wlo + flat) = l;
}

__device__ inline void split8(f32x4 v0, f32x4 v1, bf16x8& hi, bf16x8& lo) {
  u16x8 h, l;
  h[0] = f2bf(v0.x); l[0] = f2bf(v0.x - bf2f(h[0]));
  h[1] = f2bf(v0.y); l[1] = f2bf(v0.y - bf2f(h[1]));
  h[2] = f2bf(v0.z); l[2] = f2bf(v0.z - bf2f(h[2]));
  h[3] = f2bf(v0.w); l[3] = f2bf(v0.w - bf2f(h[3]));
  h[4] = f2bf(v1.x); l[4] = f2bf(v1.x - bf2f(h[4]));
  h[5] = f2bf(v1.y); l[5] = f2bf(v1.y - bf2f(h[5]));
  h[6] = f2bf(v1.z); l[6] = f2bf(v1.z - bf2f(h[6]));
  h[7] = f2bf(v1.w); l[7] = f2bf(v1.w - bf2f(h[7]));
  hi = __builtin_bit_cast(bf16x8, h);
  lo = __builtin_bit_cast(bf16x8, l);
}

// LDS gate planes: word idx = g*8192 + t*256 + (c ^ (((t>>2)&1)<<4)); <=2-way conflicts.
#define LDSW(g_, t_, c_) ((g_)*8192 + (t_)*256 + ((c_) ^ ((((t_) >> 2) & 1) << 4)))

// Fused split-bf16 gate GEMM + chunk scan. NG=3: z,i,f -> summ. NG=4: +o, uses
// states, writes h. Block = (b, kc, hd); 4 waves = 4 gates; two 32-step halves.
template <int NG>
__global__ __launch_bounds__(256, 1)
void fused_pass(const float* __restrict__ x,
                const unsigned short* __restrict__ Whi,
                const unsigned short* __restrict__ Wlo,
                const f32x4* __restrict__ states,
                f32x4* __restrict__ summ,
                float* __restrict__ out) {
  extern __shared__ float gsm[];  // [4][32][256] fp32 = 131072 B

  int bid = blockIdx.x;           // 2048 = 8 b * 64 kc * 4 hd
  int b = bid >> 8;
  int kc = (bid >> 2) & 63;
  int hd = bid & 3;
  int s0 = kc * LCH;

  int tid = threadIdx.x, lane = tid & 63, g = tid >> 6;
  int lr = lane & 15;             // A row / B col / C col
  int hi2 = lane >> 4;            // k-group & C row-group
  int lkb = hi2 << 3;             // k elem offset 0/8/16/24

  const float* xbase = x + ((size_t)(b * 4096 + s0)) * 1024 + hd * 256;
  const unsigned short* wh = Whi + (((size_t)((g << 2) | hd)) << 16);  // [256 o][256 k]
  const unsigned short* wl = Wlo + (((size_t)((g << 2) | hd)) << 16);

  int chan = (b << 10) + (hd << 8) + tid;
  float c_, n_, m_, sf = 0.f;
  if (NG == 3) {
    c_ = 0.f; n_ = 0.f; m_ = -INFINITY;
  } else {
    f32x4 st = states[(size_t)kc * CH + chan];
    c_ = st.x; n_ = st.y; m_ = st.z;
  }
  float* op = out + ((size_t)(b * 4096 + s0)) * 1024 + (hd << 8) + tid;

  for (int h2 = 0; h2 < 2; ++h2) {
    f32x4 acc[4][2][4] = {};  // [cg][mf][nf]
    if (NG == 4 || g < 3) {
#pragma unroll 2
      for (int ks = 0; ks < 8; ++ks) {
        bf16x8 ah[2], al[2];
#pragma unroll
        for (int mf = 0; mf < 2; ++mf) {
          const float* xp = xbase + (size_t)(h2 * 32 + mf * 16 + lr) * 1024 + ks * 32 + lkb;
          f32x4 v0 = *(const f32x4*)xp;
          f32x4 v1 = *(const f32x4*)(xp + 4);
          split8(v0, v1, ah[mf], al[mf]);
        }
#pragma unroll
        for (int cg = 0; cg < 4; ++cg) {
          bf16x8 bh[4], bl[4];
#pragma unroll
          for (int nf = 0; nf < 4; ++nf) {
            size_t off = (size_t)(cg * 64 + nf * 16 + lr) * 256 + ks * 32 + lkb;
            bh[nf] = *reinterpret_cast<const bf16x8*>(wh + off);
            bl[nf] = *reinterpret_cast<const bf16x8*>(wl + off);
          }
#pragma unroll
          for (int mf = 0; mf < 2; ++mf)
#pragma unroll
            for (int nf = 0; nf < 4; ++nf) {
              acc[cg][mf][nf] = __builtin_amdgcn_mfma_f32_16x16x32_bf16(
                  ah[mf], bh[nf], acc[cg][mf][nf], 0, 0, 0);
              acc[cg][mf][nf] = __builtin_amdgcn_mfma_f32_16x16x32_bf16(
                  al[mf], bh[nf], acc[cg][mf][nf], 0, 0, 0);
              acc[cg][mf][nf] = __builtin_amdgcn_mfma_f32_16x16x32_bf16(
                  ah[mf], bl[nf], acc[cg][mf][nf], 0, 0, 0);
            }
        }
      }
      // C/D: col = lane&15, row = hi2*4 + j (m89-verified); store fp32 to LDS
#pragma unroll
      for (int cg = 0; cg < 4; ++cg)
#pragma unroll
        for (int mf = 0; mf < 2; ++mf)
#pragma unroll
          for (int nf = 0; nf < 4; ++nf) {
            int cc = cg * 64 + nf * 16 + lr;
#pragma unroll
            for (int j = 0; j < 4; ++j) {
              int tl = mf * 16 + hi2 * 4 + j;
              gsm[LDSW(g, tl, cc)] = acc[cg][mf][nf][j];
            }
          }
    }
    __syncthreads();

    // ---- scan 32 steps; thread tid owns channel tid of this head
    float vz = gsm[LDSW(0, 0, tid)];
    float vi = gsm[LDSW(1, 0, tid)];
    float vf = gsm[LDSW(2, 0, tid)];
    float vo = (NG == 4) ? gsm[LDSW(3, 0, tid)] : 0.f;
#pragma unroll 4
    for (int t = 0; t < 32; ++t) {
      float nz = 0.f, ni = 0.f, nff = 0.f, no = 0.f;
      if (t < 31) {
        nz = gsm[LDSW(0, t + 1, tid)];
        ni = gsm[LDSW(1, t + 1, tid)];
        nff = gsm[LDSW(2, t + 1, tid)];
        if (NG == 4) no = gsm[LDSW(3, t + 1, tid)];
      }
      float z = tanhf(vz);
      float mn = fmaxf(vf + m_, vi);
      float ih = __expf(vi - mn);
      float fh = __expf(vf + m_ - mn);
      c_ = fh * c_ + ih * z;
      n_ = fh * n_ + ih;
      m_ = mn;
      if (NG == 3) {
        sf += vf;
      } else {
        float og = 1.f / (1.f + __expf(-vo));
        op[(size_t)(h2 * 32 + t) * 1024] = og * (c_ / (n_ + 1e-8f));
      }
      vz = nz; vi = ni; vf = nff; vo = no;
    }
    __syncthreads();  // scan reads done before next half's stores
  }
  if (NG == 3) summ[(size_t)kc * CH + chan] = f32x4{sf, c_, n_, m_};
}

// ---- sequential combine over chunks; init (c,n,m)=(0,0,0) matches reference
__global__ __launch_bounds__(256) void scan_combine(const f32x4* __restrict__ summ,
                                                    f32x4* __restrict__ states) {
  int chan = blockIdx.x * 256 + threadIdx.x;
  float c = 0.f, n = 0.f, m = 0.f;
  for (int kc = 0; kc < KCH; ++kc) {
    states[(size_t)kc * CH + chan] = f32x4{c, n, m, 0.f};
    f32x4 sm = summ[(size_t)kc * CH + chan];  // (sf, c_loc, n_loc, m_loc)
    float mn = fmaxf(m + sm.x, sm.w);
    float ea = __expf(m + sm.x - mn);
    float eb = __expf(sm.w - mn);
    c = ea * c + eb * sm.y;
    n = ea * n + eb * sm.z;
    m = mn;
  }
}

extern "C" void kernel_launch(void* const* d_in, const int* in_sizes, int n_in,
                              void* d_out, int out_size, void* d_ws, size_t ws_size,
                              hipStream_t stream) {
  const float* x  = (const float*)d_in[0];
  const float* Wz = (const float*)d_in[1];
  const float* Wi = (const float*)d_in[2];
  const float* Wf = (const float*)d_in[3];
  const float* Wo = (const float*)d_in[4];
  float* out = (float*)d_out;

  char* ws = (char*)d_ws;
  unsigned short* Whi = (unsigned short*)(ws);
  unsigned short* Wlo = (unsigned short*)(ws + 2097152);
  f32x4* summ         = (f32x4*)(ws + 4194304);
  f32x4* states       = (f32x4*)(ws + 12582912);

  cvt_w<<<1024, 256, 0, stream>>>(Wz, Wi, Wf, Wo, Whi, Wlo);
  fused_pass<3><<<2048, 256, 131072, stream>>>(x, Whi, Wlo, states, summ, out);
  scan_combine<<<32, 256, 0, stream>>>(summ, states);
  fused_pass<4><<<2048, 256, 131072, stream>>>(x, Whi, Wlo, states, summ, out);
}

// Round 4
// 816.172 us; speedup vs baseline: 1.7282x; 1.7282x over previous
//
#include <hip/hip_runtime.h>
#include <hip/hip_bf16.h>

typedef __attribute__((ext_vector_type(4))) float f32x4;
typedef __attribute__((ext_vector_type(8))) __bf16 bf16x8;
typedef __attribute__((ext_vector_type(8))) unsigned short u16x8;
typedef __attribute__((ext_vector_type(4))) unsigned short u16x4;

constexpr int KCH = 64;   // chunks over S=4096
constexpr int LCH = 64;   // steps per chunk
constexpr int CH  = 8192; // channels = B*D

// ---------- ws layout (bytes) ----------
// Whi bf16:             0        .. +2097152
// Wlo bf16:             2097152  .. +2097152
// summ f32x4[64][8192]: 4194304  .. +8388608
// states:               12582912 .. +8388608
// G fp16 4 planes [32768][1024]: 20971520 .. +268435456   (fast path only)
constexpr size_t G_OFF   = 20971520;
constexpr size_t G_PLANE = 33554432;  // halves per plane
constexpr size_t FAST_NEED = G_OFF + 4 * G_PLANE * sizeof(_Float16);  // 289,406,976

__device__ inline unsigned short f2bf(float f) {
  return __builtin_bit_cast(unsigned short, __float2bfloat16(f));
}
__device__ inline float bf2f(unsigned short u) {
  return __builtin_bit_cast(float, (unsigned)u << 16);
}

__global__ __launch_bounds__(256) void cvt_w(const float* __restrict__ Wz,
                                             const float* __restrict__ Wi,
                                             const float* __restrict__ Wf,
                                             const float* __restrict__ Wo,
                                             unsigned short* __restrict__ Whi,
                                             unsigned short* __restrict__ Wlo) {
  int i = blockIdx.x * 256 + threadIdx.x;
  int flat = i << 2;
  int g = flat >> 18;
  int rest = flat & 262143;
  const float* src = (g == 0) ? Wz : (g == 1) ? Wi : (g == 2) ? Wf : Wo;
  f32x4 v = *(const f32x4*)(src + rest);
  u16x4 h, l;
#pragma unroll
  for (int j = 0; j < 4; ++j) {
    h[j] = f2bf(v[j]);
    l[j] = f2bf(v[j] - bf2f(h[j]));
  }
  *(u16x4*)(Whi + flat) = h;
  *(u16x4*)(Wlo + flat) = l;
}

__device__ inline void split8(f32x4 v0, f32x4 v1, bf16x8& hi, bf16x8& lo) {
  u16x8 h, l;
  h[0] = f2bf(v0.x); l[0] = f2bf(v0.x - bf2f(h[0]));
  h[1] = f2bf(v0.y); l[1] = f2bf(v0.y - bf2f(h[1]));
  h[2] = f2bf(v0.z); l[2] = f2bf(v0.z - bf2f(h[2]));
  h[3] = f2bf(v0.w); l[3] = f2bf(v0.w - bf2f(h[3]));
  h[4] = f2bf(v1.x); l[4] = f2bf(v1.x - bf2f(h[4]));
  h[5] = f2bf(v1.y); l[5] = f2bf(v1.y - bf2f(h[5]));
  h[6] = f2bf(v1.z); l[6] = f2bf(v1.z - bf2f(h[6]));
  h[7] = f2bf(v1.w); l[7] = f2bf(v1.w - bf2f(h[7]));
  hi = __builtin_bit_cast(bf16x8, h);
  lo = __builtin_bit_cast(bf16x8, l);
}

// ======================= FAST PATH =======================
// Split-bf16 GEMM: for each (g,h): C[32768,256] = x_h[32768,256] . W[g,h][o,k]^T
// 128x128 tile, BK=64, 4 waves, fp16 epilogue into gate plane g.
// LDS tiles [128 rows][8 chunks of 16B] with chunk-XOR swizzle c=(row<<3)+(kc^(row&7)).
__global__ __launch_bounds__(256, 2)
void gemm_split(const float* __restrict__ x,
                const unsigned short* __restrict__ Whi,
                const unsigned short* __restrict__ Wlo,
                _Float16* __restrict__ G) {
  extern __shared__ unsigned short sm[];
  unsigned short* Ah = sm;
  unsigned short* Al = sm + 8192;
  unsigned short* Bh = sm + 16384;
  unsigned short* Bl = sm + 24576;

  // XCD clustering: 8 siblings (same mt,h) -> same XCD (8192 % 8 == 0, bijective)
  int orig = (blockIdx.x & 7) * 1024 + (blockIdx.x >> 3);
  int mt = orig >> 5;
  int h  = (orig >> 3) & 3;
  int g  = (orig >> 1) & 3;
  int nt = orig & 1;
  int r0 = mt << 7;
  int o0 = nt << 7;

  int tid = threadIdx.x, lane = tid & 63, wave = tid >> 6;
  int wm = wave >> 1, wn = wave & 1;
  int lr = lane & 15, hi2 = lane >> 4;

  const unsigned short* whB = Whi + (((size_t)((g << 2) | h)) << 16);  // [256 o][256 k]
  const unsigned short* wlB = Wlo + (((size_t)((g << 2) | h)) << 16);

  int arow = tid >> 1;                 // A-stage: 2 threads per row
  int akb  = (tid & 1) << 5;           // k-half within BK=64
  const float* xrow = x + (size_t)(r0 + arow) * 1024 + (h << 8) + akb;

  f32x4 acc[4][4] = {};

  for (int kt = 0; kt < 4; ++kt) {
    int k0 = kt << 6;
    // ---- stage A: fp32 -> split bf16 hi/lo -> LDS (swizzled)
    {
      const float* xp = xrow + k0;
#pragma unroll
      for (int p = 0; p < 4; ++p) {
        f32x4 v0 = *(const f32x4*)(xp + p * 8);
        f32x4 v1 = *(const f32x4*)(xp + p * 8 + 4);
        bf16x8 hh, ll;
        split8(v0, v1, hh, ll);
        int kc = (akb >> 3) + p;                       // 0..7
        int cidx = (arow << 3) + (kc ^ (arow & 7));
        *(bf16x8*)(Ah + cidx * 8) = hh;
        *(bf16x8*)(Al + cidx * 8) = ll;
      }
    }
    // ---- stage B: global_load_lds, linear dest + inverse-swizzled source
#pragma unroll
    for (int i = 0; i < 4; ++i) {
      int c = (i << 8) + tid;
      int row = c >> 3;
      int kcd = (c & 7) ^ (row & 7);
      const unsigned short* hs = whB + (size_t)(o0 + row) * 256 + k0 + (kcd << 3);
      const unsigned short* ls = wlB + (size_t)(o0 + row) * 256 + k0 + (kcd << 3);
      __builtin_amdgcn_global_load_lds(
          (const __attribute__((address_space(1))) void*)hs,
          (__attribute__((address_space(3))) void*)(Bh + c * 8), 16, 0, 0);
      __builtin_amdgcn_global_load_lds(
          (const __attribute__((address_space(1))) void*)ls,
          (__attribute__((address_space(3))) void*)(Bl + c * 8), 16, 0, 0);
    }
    __syncthreads();
#pragma unroll
    for (int ks = 0; ks < 2; ++ks) {
      int kcf = (ks << 2) + hi2;       // frag chunk 0..7
      bf16x8 ah[4], al[4], bh[4], bl[4];
#pragma unroll
      for (int mf = 0; mf < 4; ++mf) {
        int row = (wm << 6) + (mf << 4) + lr;
        int cidx = (row << 3) + (kcf ^ (row & 7));
        ah[mf] = *(const bf16x8*)(Ah + cidx * 8);
        al[mf] = *(const bf16x8*)(Al + cidx * 8);
      }
#pragma unroll
      for (int nf = 0; nf < 4; ++nf) {
        int row = (wn << 6) + (nf << 4) + lr;
        int cidx = (row << 3) + (kcf ^ (row & 7));
        bh[nf] = *(const bf16x8*)(Bh + cidx * 8);
        bl[nf] = *(const bf16x8*)(Bl + cidx * 8);
      }
#pragma unroll
      for (int mf = 0; mf < 4; ++mf)
#pragma unroll
        for (int nf = 0; nf < 4; ++nf) {
          acc[mf][nf] = __builtin_amdgcn_mfma_f32_16x16x32_bf16(ah[mf], bh[nf], acc[mf][nf], 0, 0, 0);
          acc[mf][nf] = __builtin_amdgcn_mfma_f32_16x16x32_bf16(al[mf], bh[nf], acc[mf][nf], 0, 0, 0);
          acc[mf][nf] = __builtin_amdgcn_mfma_f32_16x16x32_bf16(ah[mf], bl[nf], acc[mf][nf], 0, 0, 0);
        }
    }
    __syncthreads();
  }
  // ---- epilogue: C/D col=lane&15, row=(lane>>4)*4+j (m89-verified); fp16 store
  _Float16* Gg = G + (size_t)g * G_PLANE;
#pragma unroll
  for (int mf = 0; mf < 4; ++mf)
#pragma unroll
    for (int nf = 0; nf < 4; ++nf) {
      int col = (h << 8) + o0 + (wn << 6) + (nf << 4) + lr;
      int rowb = r0 + (wm << 6) + (mf << 4) + (hi2 << 2);
#pragma unroll
      for (int j = 0; j < 4; ++j)
        Gg[(size_t)(rowb + j) * 1024 + col] = (_Float16)acc[mf][nf][j];
    }
}

__global__ __launch_bounds__(256) void scan_partial_g(const _Float16* __restrict__ G,
                                                      f32x4* __restrict__ summ) {
  int kc = blockIdx.x >> 5;
  int cb = blockIdx.x & 31;
  int chan = cb * 256 + threadIdx.x;
  int b = chan >> 10, d = chan & 1023;
  size_t base = (size_t)(b * 4096 + kc * LCH) * 1024 + d;
  const _Float16* Gz = G + base;
  const _Float16* Gi = G + G_PLANE + base;
  const _Float16* Gf = G + 2 * G_PLANE + base;

  float m = -INFINITY, c = 0.f, n = 0.f, sf = 0.f;
  constexpr int P = 8;
  float bz[P], bi[P], bff[P];
#pragma unroll
  for (int j = 0; j < P; ++j) {
    size_t off = (size_t)j * 1024;
    bz[j] = (float)Gz[off]; bi[j] = (float)Gi[off]; bff[j] = (float)Gf[off];
  }
#pragma unroll 1
  for (int t0 = 0; t0 < LCH; t0 += P) {
#pragma unroll
    for (int j = 0; j < P; ++j) {
      float zt = bz[j], it = bi[j], ft = bff[j];
      int tn = t0 + j + P;
      if (tn < LCH) {
        size_t off = (size_t)tn * 1024;
        bz[j] = (float)Gz[off]; bi[j] = (float)Gi[off]; bff[j] = (float)Gf[off];
      }
      float z = tanhf(zt);
      float mn = fmaxf(ft + m, it);
      float ih = __expf(it - mn);
      float fh = __expf(ft + m - mn);
      c = fh * c + ih * z;
      n = fh * n + ih;
      m = mn;
      sf += ft;
    }
  }
  summ[(size_t)kc * CH + chan] = f32x4{sf, c, n, m};
}

__global__ __launch_bounds__(256) void scan_apply_g(const _Float16* __restrict__ G,
                                                    const f32x4* __restrict__ states,
                                                    float* __restrict__ out) {
  int kc = blockIdx.x >> 5;
  int cb = blockIdx.x & 31;
  int chan = cb * 256 + threadIdx.x;
  int b = chan >> 10, d = chan & 1023;
  size_t base = (size_t)(b * 4096 + kc * LCH) * 1024 + d;
  const _Float16* Gz = G + base;
  const _Float16* Gi = G + G_PLANE + base;
  const _Float16* Gf = G + 2 * G_PLANE + base;
  const _Float16* Go = G + 3 * G_PLANE + base;
  float* op = out + base;

  f32x4 st = states[(size_t)kc * CH + chan];
  float c = st.x, n = st.y, m = st.z;
  constexpr int P = 8;
  float bz[P], bi[P], bff[P], bo[P];
#pragma unroll
  for (int j = 0; j < P; ++j) {
    size_t off = (size_t)j * 1024;
    bz[j] = (float)Gz[off]; bi[j] = (float)Gi[off];
    bff[j] = (float)Gf[off]; bo[j] = (float)Go[off];
  }
#pragma unroll 1
  for (int t0 = 0; t0 < LCH; t0 += P) {
#pragma unroll
    for (int j = 0; j < P; ++j) {
      float zt = bz[j], it = bi[j], ft = bff[j], ot = bo[j];
      int tn = t0 + j + P;
      if (tn < LCH) {
        size_t off = (size_t)tn * 1024;
        bz[j] = (float)Gz[off]; bi[j] = (float)Gi[off];
        bff[j] = (float)Gf[off]; bo[j] = (float)Go[off];
      }
      float z = tanhf(zt);
      float og = 1.f / (1.f + __expf(-ot));
      float mn = fmaxf(ft + m, it);
      float ih = __expf(it - mn);
      float fh = __expf(ft + m - mn);
      c = fh * c + ih * z;
      n = fh * n + ih;
      m = mn;
      op[(size_t)(t0 + j) * 1024] = og * (c / (n + 1e-8f));
    }
  }
}

// ======================= FALLBACK (R3, verified) =======================
#define LDSW(g_, t_, c_) ((g_)*8192 + (t_)*256 + ((c_) ^ ((((t_) >> 2) & 1) << 4)))

template <int NG>
__global__ __launch_bounds__(256, 1)
void fused_pass(const float* __restrict__ x,
                const unsigned short* __restrict__ Whi,
                const unsigned short* __restrict__ Wlo,
                const f32x4* __restrict__ states,
                f32x4* __restrict__ summ,
                float* __restrict__ out) {
  extern __shared__ float gsm[];

  int bid = blockIdx.x;
  int b = bid >> 8;
  int kc = (bid >> 2) & 63;
  int hd = bid & 3;
  int s0 = kc * LCH;

  int tid = threadIdx.x, lane = tid & 63, g = tid >> 6;
  int lr = lane & 15;
  int hi2 = lane >> 4;
  int lkb = hi2 << 3;

  const float* xbase = x + ((size_t)(b * 4096 + s0)) * 1024 + hd * 256;
  const unsigned short* wh = Whi + (((size_t)((g << 2) | hd)) << 16);
  const unsigned short* wl = Wlo + (((size_t)((g << 2) | hd)) << 16);

  int chan = (b << 10) + (hd << 8) + tid;
  float c_, n_, m_, sf = 0.f;
  if (NG == 3) {
    c_ = 0.f; n_ = 0.f; m_ = -INFINITY;
  } else {
    f32x4 st = states[(size_t)kc * CH + chan];
    c_ = st.x; n_ = st.y; m_ = st.z;
  }
  float* op = out + ((size_t)(b * 4096 + s0)) * 1024 + (hd << 8) + tid;

  for (int h2 = 0; h2 < 2; ++h2) {
    f32x4 acc[4][2][4] = {};
    if (NG == 4 || g < 3) {
#pragma unroll 2
      for (int ks = 0; ks < 8; ++ks) {
        bf16x8 ah[2], al[2];
#pragma unroll
        for (int mf = 0; mf < 2; ++mf) {
          const float* xp = xbase + (size_t)(h2 * 32 + mf * 16 + lr) * 1024 + ks * 32 + lkb;
          f32x4 v0 = *(const f32x4*)xp;
          f32x4 v1 = *(const f32x4*)(xp + 4);
          split8(v0, v1, ah[mf], al[mf]);
        }
#pragma unroll
        for (int cg = 0; cg < 4; ++cg) {
          bf16x8 bh[4], bl[4];
#pragma unroll
          for (int nf = 0; nf < 4; ++nf) {
            size_t off = (size_t)(cg * 64 + nf * 16 + lr) * 256 + ks * 32 + lkb;
            bh[nf] = *reinterpret_cast<const bf16x8*>(wh + off);
            bl[nf] = *reinterpret_cast<const bf16x8*>(wl + off);
          }
#pragma unroll
          for (int mf = 0; mf < 2; ++mf)
#pragma unroll
            for (int nf = 0; nf < 4; ++nf) {
              acc[cg][mf][nf] = __builtin_amdgcn_mfma_f32_16x16x32_bf16(ah[mf], bh[nf], acc[cg][mf][nf], 0, 0, 0);
              acc[cg][mf][nf] = __builtin_amdgcn_mfma_f32_16x16x32_bf16(al[mf], bh[nf], acc[cg][mf][nf], 0, 0, 0);
              acc[cg][mf][nf] = __builtin_amdgcn_mfma_f32_16x16x32_bf16(ah[mf], bl[nf], acc[cg][mf][nf], 0, 0, 0);
            }
        }
      }
#pragma unroll
      for (int cg = 0; cg < 4; ++cg)
#pragma unroll
        for (int mf = 0; mf < 2; ++mf)
#pragma unroll
          for (int nf = 0; nf < 4; ++nf) {
            int cc = cg * 64 + nf * 16 + lr;
#pragma unroll
            for (int j = 0; j < 4; ++j) {
              int tl = mf * 16 + hi2 * 4 + j;
              gsm[LDSW(g, tl, cc)] = acc[cg][mf][nf][j];
            }
          }
    }
    __syncthreads();

    float vz = gsm[LDSW(0, 0, tid)];
    float vi = gsm[LDSW(1, 0, tid)];
    float vf = gsm[LDSW(2, 0, tid)];
    float vo = (NG == 4) ? gsm[LDSW(3, 0, tid)] : 0.f;
#pragma unroll 4
    for (int t = 0; t < 32; ++t) {
      float nz = 0.f, ni = 0.f, nff = 0.f, no = 0.f;
      if (t < 31) {
        nz = gsm[LDSW(0, t + 1, tid)];
        ni = gsm[LDSW(1, t + 1, tid)];
        nff = gsm[LDSW(2, t + 1, tid)];
        if (NG == 4) no = gsm[LDSW(3, t + 1, tid)];
      }
      float z = tanhf(vz);
      float mn = fmaxf(vf + m_, vi);
      float ih = __expf(vi - mn);
      float fh = __expf(vf + m_ - mn);
      c_ = fh * c_ + ih * z;
      n_ = fh * n_ + ih;
      m_ = mn;
      if (NG == 3) {
        sf += vf;
      } else {
        float og = 1.f / (1.f + __expf(-vo));
        op[(size_t)(h2 * 32 + t) * 1024] = og * (c_ / (n_ + 1e-8f));
      }
      vz = nz; vi = ni; vf = nff; vo = no;
    }
    __syncthreads();
  }
  if (NG == 3) summ[(size_t)kc * CH + chan] = f32x4{sf, c_, n_, m_};
}

__global__ __launch_bounds__(256) void scan_combine(const f32x4* __restrict__ summ,
                                                    f32x4* __restrict__ states) {
  int chan = blockIdx.x * 256 + threadIdx.x;
  float c = 0.f, n = 0.f, m = 0.f;
  for (int kc = 0; kc < KCH; ++kc) {
    states[(size_t)kc * CH + chan] = f32x4{c, n, m, 0.f};
    f32x4 sm = summ[(size_t)kc * CH + chan];
    float mn = fmaxf(m + sm.x, sm.w);
    float ea = __expf(m + sm.x - mn);
    float eb = __expf(sm.w - mn);
    c = ea * c + eb * sm.y;
    n = ea * n + eb * sm.z;
    m = mn;
  }
}

extern "C" void kernel_launch(void* const* d_in, const int* in_sizes, int n_in,
                              void* d_out, int out_size, void* d_ws, size_t ws_size,
                              hipStream_t stream) {
  const float* x  = (const float*)d_in[0];
  const float* Wz = (const float*)d_in[1];
  const float* Wi = (const float*)d_in[2];
  const float* Wf = (const float*)d_in[3];
  const float* Wo = (const float*)d_in[4];
  float* out = (float*)d_out;

  char* ws = (char*)d_ws;
  unsigned short* Whi = (unsigned short*)(ws);
  unsigned short* Wlo = (unsigned short*)(ws + 2097152);
  f32x4* summ         = (f32x4*)(ws + 4194304);
  f32x4* states       = (f32x4*)(ws + 12582912);

  cvt_w<<<1024, 256, 0, stream>>>(Wz, Wi, Wf, Wo, Whi, Wlo);

  if (ws_size >= FAST_NEED) {
    _Float16* G = (_Float16*)(ws + G_OFF);
    gemm_split<<<8192, 256, 65536, stream>>>(x, Whi, Wlo, G);
    scan_partial_g<<<2048, 256, 0, stream>>>(G, summ);
    scan_combine<<<32, 256, 0, stream>>>(summ, states);
    scan_apply_g<<<2048, 256, 0, stream>>>(G, states, out);
  } else {
    fused_pass<3><<<2048, 256, 131072, stream>>>(x, Whi, Wlo, states, summ, out);
    scan_combine<<<32, 256, 0, stream>>>(summ, states);
    fused_pass<4><<<2048, 256, 131072, stream>>>(x, Whi, Wlo, states, summ, out);
  }
}

// Round 5
// 654.331 us; speedup vs baseline: 2.1556x; 1.2473x over previous
//
#include <hip/hip_runtime.h>
#include <hip/hip_bf16.h>

typedef __attribute__((ext_vector_type(4))) float f32x4;
typedef __attribute__((ext_vector_type(8))) _Float16 f16x8;
typedef __attribute__((ext_vector_type(4))) _Float16 f16x4;

constexpr int KCH = 64;   // chunks over S=4096
constexpr int LCH = 64;   // steps per chunk
constexpr int CH  = 8192; // channels = B*D

// ---------- ws layout (bytes), ~289 MB (proven available in R4) ----------
// Whf f16 [g][h][o][k]: 0        .. +2097152
// Wlf f16 [g][h][o][k]: 2097152  .. +2097152
// summ f32x4[64][8192]: 4194304  .. +8388608
// states:               12582912 .. +8388608
// G4 f16 [32768][1024][4g]: 20971520 .. +268435456
constexpr size_t G_OFF = 20971520;

__global__ __launch_bounds__(256) void cvt_w(const float* __restrict__ Wz,
                                             const float* __restrict__ Wi,
                                             const float* __restrict__ Wf,
                                             const float* __restrict__ Wo,
                                             _Float16* __restrict__ Whf,
                                             _Float16* __restrict__ Wlf) {
  int i = blockIdx.x * 256 + threadIdx.x;
  int flat = i << 2;
  int g = flat >> 18;
  int rest = flat & 262143;                 // [h][o][k]
  const float* src = (g == 0) ? Wz : (g == 1) ? Wi : (g == 2) ? Wf : Wo;
  f32x4 v = *(const f32x4*)(src + rest);
  f16x4 h, l;
#pragma unroll
  for (int j = 0; j < 4; ++j) {
    h[j] = (_Float16)v[j];
    l[j] = (_Float16)(v[j] - (float)h[j]);
  }
  *(f16x4*)(Whf + flat) = h;
  *(f16x4*)(Wlf + flat) = l;
}

// ======================= gate GEMM (f16, 2-MFMA W-split) =======================
// For each (g,h): C[32768,256] = f16(x_h)[32768,256] . (Wh+Wl)[o,k]^T
// 128x128 tile, BK=64, 4 waves, LDS 48KB -> 3 blocks/CU.
// LDS tiles [128 rows][8 chunks of 16B], chunk-XOR swizzle c=(row<<3)+(kc^(row&7)).
// Epilogue writes interleaved G4[row][d][g] fp16.
__global__ __launch_bounds__(256, 3)
void gemm_f16(const float* __restrict__ x,
              const _Float16* __restrict__ Whf,
              const _Float16* __restrict__ Wlf,
              _Float16* __restrict__ G4) {
  extern __shared__ _Float16 sm[];
  _Float16* Af = sm;           // 16 KB
  _Float16* Bh = sm + 8192;    // 16 KB
  _Float16* Bl = sm + 16384;   // 16 KB

  // sibling-coherent XCD swizzle (verified R4): 8 blocks sharing the A-tile
  // (g,nt of same mt,h) land on one XCD.
  int orig = (blockIdx.x & 7) * 1024 + (blockIdx.x >> 3);
  int mt = orig >> 5;
  int h  = (orig >> 3) & 3;
  int g  = (orig >> 1) & 3;
  int nt = orig & 1;
  int r0 = mt << 7;
  int o0 = nt << 7;

  int tid = threadIdx.x, lane = tid & 63, wave = tid >> 6;
  int wm = wave >> 1, wn = wave & 1;
  int lr = lane & 15, hi2 = lane >> 4;

  const _Float16* whB = Whf + (((size_t)((g << 2) | h)) << 16);  // [256 o][256 k]
  const _Float16* wlB = Wlf + (((size_t)((g << 2) | h)) << 16);

  int arow = tid >> 1;            // A-stage: 2 threads per row
  int akb  = (tid & 1) << 5;      // k-half within BK=64
  const float* xrow = x + (size_t)(r0 + arow) * 1024 + (h << 8) + akb;

  f32x4 acc[4][4] = {};

  for (int kt = 0; kt < 4; ++kt) {
    int k0 = kt << 6;
    // ---- stage A: fp32 -> f16 -> LDS (swizzled)
    {
      const float* xp = xrow + k0;
#pragma unroll
      for (int p = 0; p < 4; ++p) {
        f32x4 v0 = *(const f32x4*)(xp + p * 8);
        f32x4 v1 = *(const f32x4*)(xp + p * 8 + 4);
        f16x8 hv;
        hv[0] = (_Float16)v0.x; hv[1] = (_Float16)v0.y;
        hv[2] = (_Float16)v0.z; hv[3] = (_Float16)v0.w;
        hv[4] = (_Float16)v1.x; hv[5] = (_Float16)v1.y;
        hv[6] = (_Float16)v1.z; hv[7] = (_Float16)v1.w;
        int kc = (akb >> 3) + p;                  // 0..7
        int cidx = (arow << 3) + (kc ^ (arow & 7));
        *(f16x8*)(Af + cidx * 8) = hv;
      }
    }
    // ---- stage B: global_load_lds, linear dest + inverse-swizzled source
#pragma unroll
    for (int i = 0; i < 4; ++i) {
      int c = (i << 8) + tid;
      int row = c >> 3;
      int kcd = (c & 7) ^ (row & 7);
      const _Float16* hs = whB + (size_t)(o0 + row) * 256 + k0 + (kcd << 3);
      const _Float16* ls = wlB + (size_t)(o0 + row) * 256 + k0 + (kcd << 3);
      __builtin_amdgcn_global_load_lds(
          (const __attribute__((address_space(1))) void*)hs,
          (__attribute__((address_space(3))) void*)(Bh + c * 8), 16, 0, 0);
      __builtin_amdgcn_global_load_lds(
          (const __attribute__((address_space(1))) void*)ls,
          (__attribute__((address_space(3))) void*)(Bl + c * 8), 16, 0, 0);
    }
    __syncthreads();
#pragma unroll
    for (int ks = 0; ks < 2; ++ks) {
      int kcf = (ks << 2) + hi2;    // frag chunk 0..7
      f16x8 af[4], bh[4], bl[4];
#pragma unroll
      for (int mf = 0; mf < 4; ++mf) {
        int row = (wm << 6) + (mf << 4) + lr;
        int cidx = (row << 3) + (kcf ^ (row & 7));
        af[mf] = *(const f16x8*)(Af + cidx * 8);
      }
#pragma unroll
      for (int nf = 0; nf < 4; ++nf) {
        int row = (wn << 6) + (nf << 4) + lr;
        int cidx = (row << 3) + (kcf ^ (row & 7));
        bh[nf] = *(const f16x8*)(Bh + cidx * 8);
        bl[nf] = *(const f16x8*)(Bl + cidx * 8);
      }
#pragma unroll
      for (int mf = 0; mf < 4; ++mf)
#pragma unroll
        for (int nf = 0; nf < 4; ++nf) {
          acc[mf][nf] = __builtin_amdgcn_mfma_f32_16x16x32_f16(af[mf], bh[nf], acc[mf][nf], 0, 0, 0);
          acc[mf][nf] = __builtin_amdgcn_mfma_f32_16x16x32_f16(af[mf], bl[nf], acc[mf][nf], 0, 0, 0);
        }
    }
    __syncthreads();
  }
  // ---- epilogue: C/D col=lane&15, row=(lane>>4)*4+j (m89-verified); interleaved fp16
#pragma unroll
  for (int mf = 0; mf < 4; ++mf)
#pragma unroll
    for (int nf = 0; nf < 4; ++nf) {
      int col = (h << 8) + o0 + (wn << 6) + (nf << 4) + lr;
      int rowb = r0 + (wm << 6) + (mf << 4) + (hi2 << 2);
#pragma unroll
      for (int j = 0; j < 4; ++j)
        G4[(((size_t)(rowb + j) * 1024 + col) << 2) + g] = (_Float16)acc[mf][nf][j];
    }
}

// ======================= scans over interleaved G4 =======================
__global__ __launch_bounds__(256) void scan_partial_g(const _Float16* __restrict__ G4,
                                                      f32x4* __restrict__ summ) {
  int kc = blockIdx.x >> 5;
  int cb = blockIdx.x & 31;
  int chan = cb * 256 + threadIdx.x;
  int b = chan >> 10, d = chan & 1023;
  const _Float16* gp = G4 + ((size_t)(b * 4096 + kc * LCH) << 12) + (d << 2);

  float m = -INFINITY, c = 0.f, n = 0.f, sf = 0.f;
  constexpr int P = 8;
  f16x4 bg[P];
#pragma unroll
  for (int j = 0; j < P; ++j) bg[j] = *(const f16x4*)(gp + ((size_t)j << 12));
#pragma unroll 1
  for (int t0 = 0; t0 < LCH; t0 += P) {
#pragma unroll
    for (int j = 0; j < P; ++j) {
      f16x4 gv = bg[j];
      int tn = t0 + j + P;
      if (tn < LCH) bg[j] = *(const f16x4*)(gp + ((size_t)tn << 12));
      float zt = (float)gv[0], it = (float)gv[1], ft = (float)gv[2];
      float z = tanhf(zt);
      float mn = fmaxf(ft + m, it);
      float ih = __expf(it - mn);
      float fh = __expf(ft + m - mn);
      c = fh * c + ih * z;
      n = fh * n + ih;
      m = mn;
      sf += ft;
    }
  }
  summ[(size_t)kc * CH + chan] = f32x4{sf, c, n, m};
}

__global__ __launch_bounds__(256) void scan_apply_g(const _Float16* __restrict__ G4,
                                                    const f32x4* __restrict__ states,
                                                    float* __restrict__ out) {
  int kc = blockIdx.x >> 5;
  int cb = blockIdx.x & 31;
  int chan = cb * 256 + threadIdx.x;
  int b = chan >> 10, d = chan & 1023;
  const _Float16* gp = G4 + ((size_t)(b * 4096 + kc * LCH) << 12) + (d << 2);
  float* op = out + (size_t)(b * 4096 + kc * LCH) * 1024 + d;

  f32x4 st = states[(size_t)kc * CH + chan];
  float c = st.x, n = st.y, m = st.z;
  constexpr int P = 8;
  f16x4 bg[P];
#pragma unroll
  for (int j = 0; j < P; ++j) bg[j] = *(const f16x4*)(gp + ((size_t)j << 12));
#pragma unroll 1
  for (int t0 = 0; t0 < LCH; t0 += P) {
#pragma unroll
    for (int j = 0; j < P; ++j) {
      f16x4 gv = bg[j];
      int tn = t0 + j + P;
      if (tn < LCH) bg[j] = *(const f16x4*)(gp + ((size_t)tn << 12));
      float zt = (float)gv[0], it = (float)gv[1], ft = (float)gv[2], ot = (float)gv[3];
      float z = tanhf(zt);
      float og = 1.f / (1.f + __expf(-ot));
      float mn = fmaxf(ft + m, it);
      float ih = __expf(it - mn);
      float fh = __expf(ft + m - mn);
      c = fh * c + ih * z;
      n = fh * n + ih;
      m = mn;
      op[(size_t)(t0 + j) * 1024] = og * (c / (n + 1e-8f));
    }
  }
}

// ---- sequential combine over chunks; init (c,n,m)=(0,0,0) matches reference
__global__ __launch_bounds__(256) void scan_combine(const f32x4* __restrict__ summ,
                                                    f32x4* __restrict__ states) {
  int chan = blockIdx.x * 256 + threadIdx.x;
  float c = 0.f, n = 0.f, m = 0.f;
  for (int kc = 0; kc < KCH; ++kc) {
    states[(size_t)kc * CH + chan] = f32x4{c, n, m, 0.f};
    f32x4 sm = summ[(size_t)kc * CH + chan];  // (sf, c_loc, n_loc, m_loc)
    float mn = fmaxf(m + sm.x, sm.w);
    float ea = __expf(m + sm.x - mn);
    float eb = __expf(sm.w - mn);
    c = ea * c + eb * sm.y;
    n = ea * n + eb * sm.z;
    m = mn;
  }
}

extern "C" void kernel_launch(void* const* d_in, const int* in_sizes, int n_in,
                              void* d_out, int out_size, void* d_ws, size_t ws_size,
                              hipStream_t stream) {
  const float* x  = (const float*)d_in[0];
  const float* Wz = (const float*)d_in[1];
  const float* Wi = (const float*)d_in[2];
  const float* Wf = (const float*)d_in[3];
  const float* Wo = (const float*)d_in[4];
  float* out = (float*)d_out;

  char* ws = (char*)d_ws;
  _Float16* Whf = (_Float16*)(ws);
  _Float16* Wlf = (_Float16*)(ws + 2097152);
  f32x4* summ   = (f32x4*)(ws + 4194304);
  f32x4* states = (f32x4*)(ws + 12582912);
  _Float16* G4  = (_Float16*)(ws + G_OFF);

  cvt_w<<<1024, 256, 0, stream>>>(Wz, Wi, Wf, Wo, Whf, Wlf);
  gemm_f16<<<8192, 256, 49152, stream>>>(x, Whf, Wlf, G4);
  scan_partial_g<<<2048, 256, 0, stream>>>(G4, summ);
  scan_combine<<<32, 256, 0, stream>>>(summ, states);
  scan_apply_g<<<2048, 256, 0, stream>>>(G4, states, out);
}

// Round 6
// 481.767 us; speedup vs baseline: 2.9278x; 1.3582x over previous
//
#include <hip/hip_runtime.h>
#include <hip/hip_bf16.h>

typedef __attribute__((ext_vector_type(4))) float f32x4;
typedef __attribute__((ext_vector_type(8))) _Float16 f16x8;
typedef __attribute__((ext_vector_type(4))) _Float16 f16x4;

constexpr int KCH = 64;   // chunks over S=4096
constexpr int LCH = 64;   // steps per chunk
constexpr int CH  = 8192; // channels = B*D

// ---------- ws layout (bytes), ~289 MB (proven available) ----------
// Whf f16 [g][h][o][k]: 0        .. +2097152
// summ f32x4[64][8192]: 4194304  .. +8388608
// states:               12582912 .. +8388608
// G f16 4 planes [32768][1024]:  20971520 .. +268435456
constexpr size_t G_OFF   = 20971520;
constexpr size_t G_PLANE = 33554432;  // f16 elems per plane

__global__ __launch_bounds__(256) void cvt_w(const float* __restrict__ Wz,
                                             const float* __restrict__ Wi,
                                             const float* __restrict__ Wf,
                                             const float* __restrict__ Wo,
                                             _Float16* __restrict__ Whf) {
  int i = blockIdx.x * 256 + threadIdx.x;
  int flat = i << 2;
  int g = flat >> 18;
  int rest = flat & 262143;                 // [h][o][k]
  const float* src = (g == 0) ? Wz : (g == 1) ? Wi : (g == 2) ? Wf : Wo;
  f32x4 v = *(const f32x4*)(src + rest);
  f16x4 h;
#pragma unroll
  for (int j = 0; j < 4; ++j) h[j] = (_Float16)v[j];
  *(f16x4*)(Whf + flat) = h;
}

// ======================= gate GEMM (single f16) =======================
// Block: 128 rows x 128 d-cols of ONE gate plane. 512 thr (8 waves, 4m x 2n),
// BK=64, LDS 32KB, chunk-XOR swizzle. XCD swizzle keeps the 32 blocks sharing
// an A-tile (4g x 8dt) temporally adjacent on one XCD -> x fetched once.
__global__ __launch_bounds__(512, 6)
void gemm_f16(const float* __restrict__ x,
              const _Float16* __restrict__ Whf,
              _Float16* __restrict__ G) {
  extern __shared__ _Float16 sm[];
  _Float16* Af = sm;           // [128][8 chunks of 8 f16], 16 KB
  _Float16* Bf = sm + 8192;    // same, 16 KB

  int bid = blockIdx.x;                       // 8192
  int mt = (bid & 7) + ((bid >> 8) << 3);     // 0..255
  int s  = (bid >> 3) & 31;
  int g  = s & 3;
  int dt = s >> 2;                            // 0..7 -> d0 = dt*128
  int r0 = mt << 7;
  int d0 = dt << 7;
  int h  = d0 >> 8;                           // head of this d-block
  int o0 = d0 & 255;

  int tid = threadIdx.x, lane = tid & 63, wid = tid >> 6;
  int wm = wid >> 1, wn = wid & 1;            // 4m x 2n -> wave tile 32r x 64d
  int lr = lane & 15, hi2 = lane >> 4;

  const _Float16* wB = Whf + (((size_t)((g << 2) | h)) << 16);  // [256 o][256 k]

  int arow = tid >> 2;                // 4 threads per A-row
  int kq   = (tid & 3) << 4;          // 16-float k-offset
  const float* xrow = x + (size_t)(r0 + arow) * 1024 + (h << 8) + kq;

  f32x4 acc[2][4] = {};

  for (int kt = 0; kt < 4; ++kt) {
    int k0 = kt << 6;
    // ---- stage A: fp32 -> f16 -> LDS (swizzled chunks)
    {
      const float* xp = xrow + k0;
#pragma unroll
      for (int p = 0; p < 2; ++p) {
        f32x4 v0 = *(const f32x4*)(xp + p * 8);
        f32x4 v1 = *(const f32x4*)(xp + p * 8 + 4);
        f16x8 hv;
        hv[0] = (_Float16)v0.x; hv[1] = (_Float16)v0.y;
        hv[2] = (_Float16)v0.z; hv[3] = (_Float16)v0.w;
        hv[4] = (_Float16)v1.x; hv[5] = (_Float16)v1.y;
        hv[6] = (_Float16)v1.z; hv[7] = (_Float16)v1.w;
        int kc = (kq >> 3) + p;                    // chunk 0..7
        int cidx = (arow << 3) + (kc ^ (arow & 7));
        *(f16x8*)(Af + cidx * 8) = hv;
      }
    }
    // ---- stage B: global_load_lds, linear dest + inverse-swizzled source
#pragma unroll
    for (int p = 0; p < 2; ++p) {
      int c = (p << 9) + tid;           // 16B-chunk index 0..1023
      int row = c >> 3;                 // B row = d-offset 0..127
      int kcd = (c & 7) ^ (row & 7);
      const _Float16* srcp = wB + (size_t)(o0 + row) * 256 + k0 + (kcd << 3);
      __builtin_amdgcn_global_load_lds(
          (const __attribute__((address_space(1))) void*)srcp,
          (__attribute__((address_space(3))) void*)(Bf + c * 8), 16, 0, 0);
    }
    __syncthreads();
#pragma unroll
    for (int ks = 0; ks < 2; ++ks) {
      int kcf = (ks << 2) + hi2;        // frag chunk 0..7
      f16x8 af[2], bf[4];
#pragma unroll
      for (int mf = 0; mf < 2; ++mf) {
        int row = (wm << 5) + (mf << 4) + lr;
        int cidx = (row << 3) + (kcf ^ (row & 7));
        af[mf] = *(const f16x8*)(Af + cidx * 8);
      }
#pragma unroll
      for (int nf = 0; nf < 4; ++nf) {
        int row = (wn << 6) + (nf << 4) + lr;
        int cidx = (row << 3) + (kcf ^ (row & 7));
        bf[nf] = *(const f16x8*)(Bf + cidx * 8);
      }
#pragma unroll
      for (int mf = 0; mf < 2; ++mf)
#pragma unroll
        for (int nf = 0; nf < 4; ++nf)
          acc[mf][nf] = __builtin_amdgcn_mfma_f32_16x16x32_f16(af[mf], bf[nf],
                                                               acc[mf][nf], 0, 0, 0);
    }
    __syncthreads();
  }
  // ---- epilogue: C/D col=lane&15, row=(lane>>4)*4+j (m89-verified); plane store
  _Float16* Gg = G + (size_t)g * G_PLANE;
#pragma unroll
  for (int mf = 0; mf < 2; ++mf)
#pragma unroll
    for (int nf = 0; nf < 4; ++nf) {
      int d = d0 + (wn << 6) + (nf << 4) + lr;
      int rowb = r0 + (wm << 5) + (mf << 4) + (hi2 << 2);
#pragma unroll
      for (int j = 0; j < 4; ++j)
        Gg[(size_t)(rowb + j) * 1024 + d] = (_Float16)acc[mf][nf][j];
    }
}

// ======================= LDS-staged scans over G planes =======================
// Block: one chunk (64 t) x 256 channels. Stage 16-t subtiles of NP planes via
// f16x8 loads (reg-prefetch overlaps next stage with current scan), scan in LDS.
__global__ __launch_bounds__(256) void scan_partial_g(const _Float16* __restrict__ G,
                                                      f32x4* __restrict__ summ) {
  __shared__ _Float16 Ls[3 * 16 * 256];   // 24 KB
  int kc = blockIdx.x >> 5;
  int cb = blockIdx.x & 31;
  int b = cb >> 2;
  int d0 = (cb & 3) << 8;
  int tid = threadIdx.x;
  size_t base = (size_t)(b * 4096 + kc * LCH) * 1024 + d0;

  f16x8 rbuf[3][2];
#pragma unroll
  for (int p = 0; p < 3; ++p)
#pragma unroll
    for (int lp = 0; lp < 2; ++lp) {
      int li = (lp << 8) + tid;
      int t = li >> 5, dc = (li & 31) << 3;
      rbuf[p][lp] = *(const f16x8*)(G + p * G_PLANE + base + (size_t)t * 1024 + dc);
    }

  float m = -INFINITY, c = 0.f, n = 0.f, sf = 0.f;
  for (int st = 0; st < 4; ++st) {
#pragma unroll
    for (int p = 0; p < 3; ++p)
#pragma unroll
      for (int lp = 0; lp < 2; ++lp) {
        int li = (lp << 8) + tid;
        int t = li >> 5, dc = (li & 31) << 3;
        *(f16x8*)(&Ls[((p << 4) + t << 8) + dc]) = rbuf[p][lp];
      }
    __syncthreads();
    if (st < 3) {
#pragma unroll
      for (int p = 0; p < 3; ++p)
#pragma unroll
        for (int lp = 0; lp < 2; ++lp) {
          int li = (lp << 8) + tid;
          int t = li >> 5, dc = (li & 31) << 3;
          rbuf[p][lp] = *(const f16x8*)(G + p * G_PLANE + base +
                                        (size_t)((st + 1) * 16 + t) * 1024 + dc);
        }
    }
#pragma unroll 4
    for (int t = 0; t < 16; ++t) {
      float zt = (float)Ls[(t << 8) + tid];
      float it = (float)Ls[((16 + t) << 8) + tid];
      float ft = (float)Ls[((32 + t) << 8) + tid];
      float z = tanhf(zt);
      float mn = fmaxf(ft + m, it);
      float ih = __expf(it - mn);
      float fh = __expf(ft + m - mn);
      c = fh * c + ih * z;
      n = fh * n + ih;
      m = mn;
      sf += ft;
    }
    __syncthreads();
  }
  int chan = (b << 10) + d0 + tid;
  summ[(size_t)kc * CH + chan] = f32x4{sf, c, n, m};
}

__global__ __launch_bounds__(256) void scan_apply_g(const _Float16* __restrict__ G,
                                                    const f32x4* __restrict__ states,
                                                    float* __restrict__ out) {
  __shared__ _Float16 Ls[4 * 16 * 256];   // 32 KB
  int kc = blockIdx.x >> 5;
  int cb = blockIdx.x & 31;
  int b = cb >> 2;
  int d0 = (cb & 3) << 8;
  int tid = threadIdx.x;
  size_t base = (size_t)(b * 4096 + kc * LCH) * 1024 + d0;
  float* op = out + base + tid;

  f16x8 rbuf[4][2];
#pragma unroll
  for (int p = 0; p < 4; ++p)
#pragma unroll
    for (int lp = 0; lp < 2; ++lp) {
      int li = (lp << 8) + tid;
      int t = li >> 5, dc = (li & 31) << 3;
      rbuf[p][lp] = *(const f16x8*)(G + p * G_PLANE + base + (size_t)t * 1024 + dc);
    }

  int chan = (b << 10) + d0 + tid;
  f32x4 stv = states[(size_t)kc * CH + chan];
  float c = stv.x, n = stv.y, m = stv.z;

  for (int st = 0; st < 4; ++st) {
#pragma unroll
    for (int p = 0; p < 4; ++p)
#pragma unroll
      for (int lp = 0; lp < 2; ++lp) {
        int li = (lp << 8) + tid;
        int t = li >> 5, dc = (li & 31) << 3;
        *(f16x8*)(&Ls[((p << 4) + t << 8) + dc]) = rbuf[p][lp];
      }
    __syncthreads();
    if (st < 3) {
#pragma unroll
      for (int p = 0; p < 4; ++p)
#pragma unroll
        for (int lp = 0; lp < 2; ++lp) {
          int li = (lp << 8) + tid;
          int t = li >> 5, dc = (li & 31) << 3;
          rbuf[p][lp] = *(const f16x8*)(G + p * G_PLANE + base +
                                        (size_t)((st + 1) * 16 + t) * 1024 + dc);
        }
    }
#pragma unroll 4
    for (int t = 0; t < 16; ++t) {
      float zt = (float)Ls[(t << 8) + tid];
      float it = (float)Ls[((16 + t) << 8) + tid];
      float ft = (float)Ls[((32 + t) << 8) + tid];
      float ot = (float)Ls[((48 + t) << 8) + tid];
      float z = tanhf(zt);
      float og = 1.f / (1.f + __expf(-ot));
      float mn = fmaxf(ft + m, it);
      float ih = __expf(it - mn);
      float fh = __expf(ft + m - mn);
      c = fh * c + ih * z;
      n = fh * n + ih;
      m = mn;
      op[(size_t)(st * 16 + t) * 1024] = og * (c / (n + 1e-8f));
    }
    __syncthreads();
  }
}

// ---- sequential combine over chunks; init (c,n,m)=(0,0,0) matches reference
__global__ __launch_bounds__(256) void scan_combine(const f32x4* __restrict__ summ,
                                                    f32x4* __restrict__ states) {
  int chan = blockIdx.x * 256 + threadIdx.x;
  float c = 0.f, n = 0.f, m = 0.f;
  for (int kc = 0; kc < KCH; ++kc) {
    states[(size_t)kc * CH + chan] = f32x4{c, n, m, 0.f};
    f32x4 sm = summ[(size_t)kc * CH + chan];  // (sf, c_loc, n_loc, m_loc)
    float mn = fmaxf(m + sm.x, sm.w);
    float ea = __expf(m + sm.x - mn);
    float eb = __expf(sm.w - mn);
    c = ea * c + eb * sm.y;
    n = ea * n + eb * sm.z;
    m = mn;
  }
}

extern "C" void kernel_launch(void* const* d_in, const int* in_sizes, int n_in,
                              void* d_out, int out_size, void* d_ws, size_t ws_size,
                              hipStream_t stream) {
  const float* x  = (const float*)d_in[0];
  const float* Wz = (const float*)d_in[1];
  const float* Wi = (const float*)d_in[2];
  const float* Wf = (const float*)d_in[3];
  const float* Wo = (const float*)d_in[4];
  float* out = (float*)d_out;

  char* ws = (char*)d_ws;
  _Float16* Whf = (_Float16*)(ws);
  f32x4* summ   = (f32x4*)(ws + 4194304);
  f32x4* states = (f32x4*)(ws + 12582912);
  _Float16* G   = (_Float16*)(ws + G_OFF);

  cvt_w<<<1024, 256, 0, stream>>>(Wz, Wi, Wf, Wo, Whf);
  gemm_f16<<<8192, 512, 32768, stream>>>(x, Whf, G);
  scan_partial_g<<<2048, 256, 0, stream>>>(G, summ);
  scan_combine<<<32, 256, 0, stream>>>(summ, states);
  scan_apply_g<<<2048, 256, 0, stream>>>(G, states, out);
}